// Round 1
// baseline (261.461 us; speedup 1.0000x reference)
//
#include <hip/hip_runtime.h>
#include <math.h>

#define BB 128
#define LL 512
#define KK 8
#define DD 300
#define CC 14
#define L_CHUNK 64

// Aggregation: X[b,d] = sum_l [ (1-N[m])*max_k(R[s_k,d]*E[e_k]) + N[m]*R[m,d] ]
__global__ __launch_bounds__(320) void gnn_agg(
    const int* __restrict__ master, const int* __restrict__ slaves,
    const int* __restrict__ edges, const float* __restrict__ R,
    const float* __restrict__ E, const float* __restrict__ N,
    float* __restrict__ X /* [B,D], zero-initialized */)
{
    const int b = blockIdx.x;
    const int lc = blockIdx.y;
    const int d = threadIdx.x;
    const bool active = (d < DD);

    float acc = 0.f;
    const int l0 = lc * L_CHUNK;

    for (int li = 0; li < L_CHUNK; ++li) {
        const int bl = b * LL + (l0 + li);
        const int m = master[bl];            // wave-broadcast load
        const float nn = N[m];               // wave-broadcast load

        const int* sl = slaves + (long)bl * KK;
        const int* ed = edges  + (long)bl * KK;

        int   s[KK];
        float e[KK];
#pragma unroll
        for (int k = 0; k < KK; ++k) s[k] = sl[k];
#pragma unroll
        for (int k = 0; k < KK; ++k) e[k] = E[ed[k]];

        if (active) {
            float mn = -INFINITY;
#pragma unroll
            for (int k = 0; k < KK; ++k) {
                const float v = R[s[k] * DD + d] * e[k];
                mn = fmaxf(mn, v);
            }
            const float rn = R[m * DD + d];
            acc += (1.f - nn) * mn + nn * rn;
        }
    }
    if (active) atomicAdd(&X[b * DD + d], acc);
}

// FC (300->14) + ReLU + softmax, one block per batch row.
__global__ __launch_bounds__(64) void fc_softmax(
    const float* __restrict__ X, const float* __restrict__ W,
    const float* __restrict__ bias, float* __restrict__ out)
{
    const int b = blockIdx.x;
    const int c = threadIdx.x;
    __shared__ float h[CC];

    if (c < CC) {
        float acc = bias[c];
        const float* x = X + b * DD;
        const float* w = W + c * DD;
        for (int d = 0; d < DD; ++d) acc += x[d] * w[d];
        h[c] = fmaxf(acc, 0.f);
    }
    __syncthreads();
    if (c < CC) {
        float m = -INFINITY;
        for (int i = 0; i < CC; ++i) m = fmaxf(m, h[i]);
        float s = 0.f;
        for (int i = 0; i < CC; ++i) s += expf(h[i] - m);
        out[b * CC + c] = expf(h[c] - m) / s;
    }
}

extern "C" void kernel_launch(void* const* d_in, const int* in_sizes, int n_in,
                              void* d_out, int out_size, void* d_ws, size_t ws_size,
                              hipStream_t stream) {
    const int*   master = (const int*)d_in[0];
    const int*   slaves = (const int*)d_in[1];
    const int*   edges  = (const int*)d_in[2];
    const float* R      = (const float*)d_in[3];
    const float* E      = (const float*)d_in[4];
    const float* N      = (const float*)d_in[5];
    const float* W      = (const float*)d_in[6];
    const float* bias   = (const float*)d_in[7];
    float* out = (float*)d_out;
    float* X   = (float*)d_ws;   // [BB, DD] partial sums

    hipMemsetAsync(X, 0, BB * DD * sizeof(float), stream);

    dim3 grid(BB, LL / L_CHUNK);
    gnn_agg<<<grid, 320, 0, stream>>>(master, slaves, edges, R, E, N, X);
    fc_softmax<<<BB, 64, 0, stream>>>(X, W, bias, out);
}

// Round 2
// 258.631 us; speedup vs baseline: 1.0109x; 1.0109x over previous
//
#include <hip/hip_runtime.h>
#include <math.h>

#define BB 128
#define LL 512
#define KK 8
#define DD 300
#define CC 14
#define L_CHUNK 32
#define UNROLL 4

// Aggregation: X[b,d] = sum_l [ (1-N[m])*max_k(R[s_k,d]*E[e_k]) + N[m]*R[m,d] ]
// Grid: (BB, LL/L_CHUNK) = (128, 16) = 2048 blocks, 320 threads (d = lane).
// 4x unrolled over l: all index + E loads for the group issued before compute
// so the E-gather latency (random over 96MB table) is overlapped 4-deep.
__global__ __launch_bounds__(320) void gnn_agg(
    const int* __restrict__ master, const int* __restrict__ slaves,
    const int* __restrict__ edges, const float* __restrict__ R,
    const float* __restrict__ E, const float* __restrict__ N,
    float* __restrict__ X /* [B,D], zero-initialized */)
{
    const int b = blockIdx.x;
    const int lc = blockIdx.y;
    const int d = threadIdx.x;
    const bool active = (d < DD);

    float acc = 0.f;
    const int l0 = lc * L_CHUNK;

    for (int lg = 0; lg < L_CHUNK; lg += UNROLL) {
        int   m[UNROLL];
        float nn[UNROLL];
        int   s[UNROLL][KK];
        int   ed[UNROLL][KK];
        float e[UNROLL][KK];

        // Phase 1: issue ALL index loads for the group (independent).
#pragma unroll
        for (int u = 0; u < UNROLL; ++u) {
            const int bl = b * LL + (l0 + lg + u);
            m[u] = master[bl];
            const int* sl = slaves + (long)bl * KK;
            const int* eg = edges  + (long)bl * KK;
#pragma unroll
            for (int k = 0; k < KK; ++k) s[u][k]  = sl[k];
#pragma unroll
            for (int k = 0; k < KK; ++k) ed[u][k] = eg[k];
        }

        // Phase 2: issue ALL E gathers + N gates (independent, high latency).
#pragma unroll
        for (int u = 0; u < UNROLL; ++u) {
            nn[u] = N[m[u]];
#pragma unroll
            for (int k = 0; k < KK; ++k) e[u][k] = E[ed[u][k]];
        }

        // Phase 3: R gathers + compute, per u (compiler overlaps across u).
        if (active) {
#pragma unroll
            for (int u = 0; u < UNROLL; ++u) {
                float r[KK];
#pragma unroll
                for (int k = 0; k < KK; ++k) r[k] = R[s[u][k] * DD + d];
                const float rn = R[m[u] * DD + d];
                float mn = r[0] * e[u][0];
#pragma unroll
                for (int k = 1; k < KK; ++k) mn = fmaxf(mn, r[k] * e[u][k]);
                acc += (1.f - nn[u]) * mn + nn[u] * rn;
            }
        }
    }
    if (active) atomicAdd(&X[b * DD + d], acc);
}

// FC (300->14) + ReLU + softmax. One block per batch row, 16 lanes per class.
__global__ __launch_bounds__(256) void fc_softmax(
    const float* __restrict__ X, const float* __restrict__ W,
    const float* __restrict__ bias, float* __restrict__ out)
{
    const int b = blockIdx.x;
    const int t = threadIdx.x;
    const int c = t >> 4;      // class, 0..13 active
    const int j = t & 15;      // lane within class group
    __shared__ float h[CC];

    if (c < CC) {
        float acc = 0.f;
        const float* x = X + b * DD;
        const float* w = W + c * DD;
        for (int d = j; d < DD; d += 16) acc += x[d] * w[d];
#pragma unroll
        for (int off = 8; off > 0; off >>= 1) acc += __shfl_down(acc, off, 16);
        if (j == 0) h[c] = fmaxf(acc + bias[c], 0.f);
    }
    __syncthreads();
    if (t < CC) {
        float mx = -INFINITY;
#pragma unroll
        for (int i = 0; i < CC; ++i) mx = fmaxf(mx, h[i]);
        float s = 0.f;
#pragma unroll
        for (int i = 0; i < CC; ++i) s += expf(h[i] - mx);
        out[b * CC + t] = expf(h[t] - mx) / s;
    }
}

extern "C" void kernel_launch(void* const* d_in, const int* in_sizes, int n_in,
                              void* d_out, int out_size, void* d_ws, size_t ws_size,
                              hipStream_t stream) {
    const int*   master = (const int*)d_in[0];
    const int*   slaves = (const int*)d_in[1];
    const int*   edges  = (const int*)d_in[2];
    const float* R      = (const float*)d_in[3];
    const float* E      = (const float*)d_in[4];
    const float* N      = (const float*)d_in[5];
    const float* W      = (const float*)d_in[6];
    const float* bias   = (const float*)d_in[7];
    float* out = (float*)d_out;
    float* X   = (float*)d_ws;   // [BB, DD] partial sums

    hipMemsetAsync(X, 0, BB * DD * sizeof(float), stream);

    dim3 grid(BB, LL / L_CHUNK);
    gnn_agg<<<grid, 320, 0, stream>>>(master, slaves, edges, R, E, N, X);
    fc_softmax<<<BB, 256, 0, stream>>>(X, W, bias, out);
}

// Round 3
// 223.745 us; speedup vs baseline: 1.1686x; 1.1559x over previous
//
#include <hip/hip_runtime.h>
#include <math.h>

#define BB 128
#define LL 512
#define KK 8
#define DD 300
#define D2 150          // D in float2 units
#define CC 14
#define L_PER_BLOCK 16

// Phase A: resolve all random gathers with max memory-level parallelism.
// One thread per (b,l,k) edge; first B*L threads also gather the N gate.
__global__ __launch_bounds__(256) void gather_en(
    const int* __restrict__ edges, const float* __restrict__ E,
    const int* __restrict__ master, const float* __restrict__ N,
    float* __restrict__ e_ws, float* __restrict__ nn_ws)
{
    const int i = blockIdx.x * 256 + threadIdx.x;   // 0 .. B*L*K-1
    e_ws[i] = E[edges[i]];
    if (i < BB * LL) nn_ws[i] = N[master[i]];
}

// Phase B: X[b,d] = sum_l [ (1-nn)*max_k(R[s_k,d]*e_k) + nn*R[m,d] ]
// 192 threads, t<150 owns one float2 of D. Per-l index/e/nn reads are
// wave-uniform -> scalar loads; vector pipe does only R float2 gathers.
__global__ __launch_bounds__(192) void gnn_agg(
    const int* __restrict__ master, const int* __restrict__ slaves,
    const float2* __restrict__ R2, const float* __restrict__ e_ws,
    const float* __restrict__ nn_ws, float* __restrict__ X)
{
    const int b  = blockIdx.x;
    const int lc = blockIdx.y;
    const int t  = threadIdx.x;
    const bool act = (t < D2);

    float accx = 0.f, accy = 0.f;
    const int bl_base = b * LL + lc * L_PER_BLOCK;

    for (int li = 0; li < L_PER_BLOCK; li += 2) {
        const int bl0 = bl_base + li;
        const int bl1 = bl0 + 1;

        // wave-uniform scalar loads
        const int   m0 = master[bl0], m1 = master[bl1];
        const float n0 = nn_ws[bl0],  n1 = nn_ws[bl1];
        int   s0[KK], s1[KK];
        float e0[KK], e1[KK];
#pragma unroll
        for (int k = 0; k < KK; ++k) { s0[k] = slaves[bl0*KK+k]; s1[k] = slaves[bl1*KK+k]; }
#pragma unroll
        for (int k = 0; k < KK; ++k) { e0[k] = e_ws[bl0*KK+k];  e1[k] = e_ws[bl1*KK+k]; }

        if (act) {
            float2 r0[KK], r1[KK];
#pragma unroll
            for (int k = 0; k < KK; ++k) r0[k] = R2[s0[k]*D2 + t];
#pragma unroll
            for (int k = 0; k < KK; ++k) r1[k] = R2[s1[k]*D2 + t];
            const float2 rm0 = R2[m0*D2 + t];
            const float2 rm1 = R2[m1*D2 + t];

            float mx0 = r0[0].x * e0[0], my0 = r0[0].y * e0[0];
            float mx1 = r1[0].x * e1[0], my1 = r1[0].y * e1[0];
#pragma unroll
            for (int k = 1; k < KK; ++k) {
                mx0 = fmaxf(mx0, r0[k].x * e0[k]);
                my0 = fmaxf(my0, r0[k].y * e0[k]);
                mx1 = fmaxf(mx1, r1[k].x * e1[k]);
                my1 = fmaxf(my1, r1[k].y * e1[k]);
            }
            accx += (1.f - n0) * mx0 + n0 * rm0.x;
            accy += (1.f - n0) * my0 + n0 * rm0.y;
            accx += (1.f - n1) * mx1 + n1 * rm1.x;
            accy += (1.f - n1) * my1 + n1 * rm1.y;
        }
    }
    if (act) {
        atomicAdd(&X[b * DD + 2*t],     accx);
        atomicAdd(&X[b * DD + 2*t + 1], accy);
    }
}

// FC (300->14) + ReLU + softmax. One block per batch row, 16 lanes per class.
__global__ __launch_bounds__(256) void fc_softmax(
    const float* __restrict__ X, const float* __restrict__ W,
    const float* __restrict__ bias, float* __restrict__ out)
{
    const int b = blockIdx.x;
    const int t = threadIdx.x;
    const int c = t >> 4;
    const int j = t & 15;
    __shared__ float h[CC];

    if (c < CC) {
        float acc = 0.f;
        const float* x = X + b * DD;
        const float* w = W + c * DD;
        for (int d = j; d < DD; d += 16) acc += x[d] * w[d];
#pragma unroll
        for (int off = 8; off > 0; off >>= 1) acc += __shfl_down(acc, off, 16);
        if (j == 0) h[c] = fmaxf(acc + bias[c], 0.f);
    }
    __syncthreads();
    if (t < CC) {
        float mx = -INFINITY;
#pragma unroll
        for (int i = 0; i < CC; ++i) mx = fmaxf(mx, h[i]);
        float s = 0.f;
#pragma unroll
        for (int i = 0; i < CC; ++i) s += expf(h[i] - mx);
        out[b * CC + t] = expf(h[t] - mx) / s;
    }
}

extern "C" void kernel_launch(void* const* d_in, const int* in_sizes, int n_in,
                              void* d_out, int out_size, void* d_ws, size_t ws_size,
                              hipStream_t stream) {
    const int*   master = (const int*)d_in[0];
    const int*   slaves = (const int*)d_in[1];
    const int*   edges  = (const int*)d_in[2];
    const float* R      = (const float*)d_in[3];
    const float* E      = (const float*)d_in[4];
    const float* N      = (const float*)d_in[5];
    const float* W      = (const float*)d_in[6];
    const float* bias   = (const float*)d_in[7];
    float* out = (float*)d_out;

    // ws layout: X [BB*DD] | nn [BB*LL] | e [BB*LL*KK]  (total ~2.5 MB)
    float* X     = (float*)d_ws;
    float* nn_ws = X + BB * DD;
    float* e_ws  = nn_ws + BB * LL;

    hipMemsetAsync(X, 0, BB * DD * sizeof(float), stream);

    gather_en<<<(BB * LL * KK) / 256, 256, 0, stream>>>(edges, E, master, N, e_ws, nn_ws);

    dim3 grid(BB, LL / L_PER_BLOCK);
    gnn_agg<<<grid, 192, 0, stream>>>(master, slaves, (const float2*)R, e_ws, nn_ws, X);

    fc_softmax<<<BB, 256, 0, stream>>>(X, W, bias, out);
}

// Round 5
// 197.353 us; speedup vs baseline: 1.3248x; 1.1337x over previous
//
#include <hip/hip_runtime.h>
#include <hip/hip_fp16.h>
#include <math.h>

#define BB 128
#define LL 512
#define KK 8
#define DD 300
#define D2 150          // D in half2 units
#define CC 14
#define L_PER_BLOCK 16

// Convert R (4905*300 fp32) -> half2 table (2.94 MB, fits per-XCD L2).
#define R_H2_ELEMS ((4905 * 300) / 2)   // 735750
__global__ __launch_bounds__(256) void cvt_R(
    const float2* __restrict__ R, __half2* __restrict__ R16)
{
    const int i = blockIdx.x * 256 + threadIdx.x;
    if (i < R_H2_ELEMS) {
        const float2 f = R[i];
        R16[i] = __floats2half2_rn(f.x, f.y);
    }
}

// Phase A: resolve all random gathers with max memory-level parallelism.
// One thread per (b,l,k) edge; first B*L threads also gather the N gate.
__global__ __launch_bounds__(256) void gather_en(
    const int* __restrict__ edges, const float* __restrict__ E,
    const int* __restrict__ master, const float* __restrict__ N,
    float* __restrict__ e_ws, float* __restrict__ nn_ws)
{
    const int i = blockIdx.x * 256 + threadIdx.x;   // 0 .. B*L*K-1
    e_ws[i] = E[edges[i]];
    if (i < BB * LL) nn_ws[i] = N[master[i]];
}

// Phase B: X[b,d] = sum_l [ (1-nn)*max_k(R[s_k,d]*e_k) + nn*R[m,d] ]
// 192 threads, t<150 owns one half2 of D. R stored fp16 (L2-resident);
// math in fp32. Per-l index/e/nn reads are wave-uniform -> scalar loads.
__global__ __launch_bounds__(192) void gnn_agg(
    const int* __restrict__ master, const int* __restrict__ slaves,
    const __half2* __restrict__ R16, const float* __restrict__ e_ws,
    const float* __restrict__ nn_ws, float* __restrict__ X)
{
    const int b  = blockIdx.x;
    const int lc = blockIdx.y;
    const int t  = threadIdx.x;
    const bool act = (t < D2);

    float accx = 0.f, accy = 0.f;
    const int bl_base = b * LL + lc * L_PER_BLOCK;

    for (int li = 0; li < L_PER_BLOCK; li += 2) {
        const int bl0 = bl_base + li;
        const int bl1 = bl0 + 1;

        // wave-uniform scalar loads
        const int   m0 = master[bl0], m1 = master[bl1];
        const float n0 = nn_ws[bl0],  n1 = nn_ws[bl1];
        const float a0 = 1.f - n0,    a1 = 1.f - n1;
        int   s0[KK], s1[KK];
        float e0[KK], e1[KK];
#pragma unroll
        for (int k = 0; k < KK; ++k) { s0[k] = slaves[bl0*KK+k]; s1[k] = slaves[bl1*KK+k]; }
#pragma unroll
        for (int k = 0; k < KK; ++k) { e0[k] = e_ws[bl0*KK+k];  e1[k] = e_ws[bl1*KK+k]; }

        if (act) {
            __half2 r0[KK], r1[KK];
#pragma unroll
            for (int k = 0; k < KK; ++k) r0[k] = R16[s0[k]*D2 + t];
#pragma unroll
            for (int k = 0; k < KK; ++k) r1[k] = R16[s1[k]*D2 + t];
            const __half2 rm0 = R16[m0*D2 + t];
            const __half2 rm1 = R16[m1*D2 + t];

            float2 f = __half22float2(r0[0]);
            float mx0 = f.x * e0[0], my0 = f.y * e0[0];
#pragma unroll
            for (int k = 1; k < KK; ++k) {
                f = __half22float2(r0[k]);
                mx0 = fmaxf(mx0, f.x * e0[k]);
                my0 = fmaxf(my0, f.y * e0[k]);
            }
            f = __half22float2(r1[0]);
            float mx1 = f.x * e1[0], my1 = f.y * e1[0];
#pragma unroll
            for (int k = 1; k < KK; ++k) {
                f = __half22float2(r1[k]);
                mx1 = fmaxf(mx1, f.x * e1[k]);
                my1 = fmaxf(my1, f.y * e1[k]);
            }
            const float2 rf0 = __half22float2(rm0);
            const float2 rf1 = __half22float2(rm1);

            accx = fmaf(a0, mx0, fmaf(n0, rf0.x, accx));
            accy = fmaf(a0, my0, fmaf(n0, rf0.y, accy));
            accx = fmaf(a1, mx1, fmaf(n1, rf1.x, accx));
            accy = fmaf(a1, my1, fmaf(n1, rf1.y, accy));
        }
    }
    if (act) {
        atomicAdd(&X[b * DD + 2*t],     accx);
        atomicAdd(&X[b * DD + 2*t + 1], accy);
    }
}

// FC (300->14) + ReLU + softmax. One block per batch row, 16 lanes per class.
__global__ __launch_bounds__(256) void fc_softmax(
    const float* __restrict__ X, const float* __restrict__ W,
    const float* __restrict__ bias, float* __restrict__ out)
{
    const int b = blockIdx.x;
    const int t = threadIdx.x;
    const int c = t >> 4;
    const int j = t & 15;
    __shared__ float h[CC];

    if (c < CC) {
        float acc = 0.f;
        const float* x = X + b * DD;
        const float* w = W + c * DD;
        for (int d = j; d < DD; d += 16) acc += x[d] * w[d];
#pragma unroll
        for (int off = 8; off > 0; off >>= 1) acc += __shfl_down(acc, off, 16);
        if (j == 0) h[c] = fmaxf(acc + bias[c], 0.f);
    }
    __syncthreads();
    if (t < CC) {
        float mx = -INFINITY;
#pragma unroll
        for (int i = 0; i < CC; ++i) mx = fmaxf(mx, h[i]);
        float s = 0.f;
#pragma unroll
        for (int i = 0; i < CC; ++i) s += expf(h[i] - mx);
        out[b * CC + t] = expf(h[t] - mx) / s;
    }
}

extern "C" void kernel_launch(void* const* d_in, const int* in_sizes, int n_in,
                              void* d_out, int out_size, void* d_ws, size_t ws_size,
                              hipStream_t stream) {
    const int*   master = (const int*)d_in[0];
    const int*   slaves = (const int*)d_in[1];
    const int*   edges  = (const int*)d_in[2];
    const float* R      = (const float*)d_in[3];
    const float* E      = (const float*)d_in[4];
    const float* N      = (const float*)d_in[5];
    const float* W      = (const float*)d_in[6];
    const float* bias   = (const float*)d_in[7];
    float* out = (float*)d_out;

    // ws layout (bytes): R16 [2,943,000->pad 2,943,104] | X [153,600] | nn [262,144] | e [2,097,152]
    char* ws = (char*)d_ws;
    __half2* R16   = (__half2*)ws;                      // 735750 half2
    float*   X     = (float*)(ws + 2943104);            // BB*DD
    float*   nn_ws = (float*)(ws + 2943104 + 153600);   // BB*LL
    float*   e_ws  = (float*)(ws + 2943104 + 153600 + 262144); // BB*LL*KK

    (void)hipMemsetAsync(X, 0, BB * DD * sizeof(float), stream);

    cvt_R<<<(R_H2_ELEMS + 255) / 256, 256, 0, stream>>>((const float2*)R, R16);
    gather_en<<<(BB * LL * KK) / 256, 256, 0, stream>>>(edges, E, master, N, e_ws, nn_ws);

    dim3 grid(BB, LL / L_PER_BLOCK);
    gnn_agg<<<grid, 192, 0, stream>>>(master, slaves, R16, e_ws, nn_ws, X);

    fc_softmax<<<BB, 256, 0, stream>>>(X, W, bias, out);
}

// Round 6
// 194.431 us; speedup vs baseline: 1.3448x; 1.0150x over previous
//
#include <hip/hip_runtime.h>
#include <hip/hip_fp16.h>
#include <math.h>

#define BB 128
#define LL 512
#define KK 8
#define DD 300
#define D2 150          // D in half2 units
#define CC 14
#define L_PER_BLOCK 16
#define UNROLL 4

#define R_H2_ELEMS ((4905 * 300) / 2)   // 735750
#define REC_INTS 20                     // per-l record: [off_m, nn, (off_s,e)*8, pad2]

// Fused prep:
//  - convert R fp32 -> half2 table (2.94 MB, per-XCD-L2-resident)
//  - resolve all random E / N gathers (one thread per edge: max MLP)
//  - write packed per-l records with pre-scaled row offsets
//  - zero X accumulator
__global__ __launch_bounds__(256) void prep(
    const float2* __restrict__ R, const int* __restrict__ edges,
    const float* __restrict__ E, const int* __restrict__ master,
    const float* __restrict__ N, const int* __restrict__ slaves,
    __half2* __restrict__ R16, int* __restrict__ rec, float* __restrict__ X)
{
    const int i = blockIdx.x * 256 + threadIdx.x;

    if (i < R_H2_ELEMS) {
        const float2 f = R[i];
        R16[i] = __floats2half2_rn(f.x, f.y);
    }
    if (i < BB * LL * KK) {                       // one edge each
        const int bl = i >> 3, k = i & 7;
        rec[bl * REC_INTS + 2 + 2 * k] = slaves[i] * D2;
        rec[bl * REC_INTS + 3 + 2 * k] = __float_as_int(E[edges[i]]);
    }
    if (i < BB * LL) {                            // master + gate
        const int m = master[i];
        rec[i * REC_INTS]     = m * D2;
        rec[i * REC_INTS + 1] = __float_as_int(N[m]);
    }
    if (i < BB * DD) X[i] = 0.f;
}

// X[b,d] = sum_l [ (1-nn)*max_k(R[s_k,d]*e_k) + nn*R[m,d] ]
// 192 threads, t<150 owns one half2 of D. Records read via uniform int4
// (-> s_load_dwordx4); 4-deep l unroll = 36 independent L2-hit gathers.
__global__ __launch_bounds__(192) void gnn_agg(
    const int4* __restrict__ rec4, const __half2* __restrict__ R16,
    float* __restrict__ X)
{
    const int b  = blockIdx.x;
    const int lc = blockIdx.y;
    const int t  = threadIdx.x;
    const bool act = (t < D2);

    float accx = 0.f, accy = 0.f;
    const int bl_base = b * LL + lc * L_PER_BLOCK;

    for (int lg = 0; lg < L_PER_BLOCK; lg += UNROLL) {
        int   offm[UNROLL], offs[UNROLL][KK];
        float nn[UNROLL], e[UNROLL][KK];

#pragma unroll
        for (int u = 0; u < UNROLL; ++u) {
            const int4* r = rec4 + (long)(bl_base + lg + u) * (REC_INTS / 4);
            const int4 q0 = r[0];   // off_m, nn, off_s0, e0
            const int4 q1 = r[1];   // off_s1, e1, off_s2, e2
            const int4 q2 = r[2];   // off_s3, e3, off_s4, e4
            const int4 q3 = r[3];   // off_s5, e5, off_s6, e6
            const int4 q4 = r[4];   // off_s7, e7, pad, pad
            offm[u] = q0.x;            nn[u]   = __int_as_float(q0.y);
            offs[u][0] = q0.z;         e[u][0] = __int_as_float(q0.w);
            offs[u][1] = q1.x;         e[u][1] = __int_as_float(q1.y);
            offs[u][2] = q1.z;         e[u][2] = __int_as_float(q1.w);
            offs[u][3] = q2.x;         e[u][3] = __int_as_float(q2.y);
            offs[u][4] = q2.z;         e[u][4] = __int_as_float(q2.w);
            offs[u][5] = q3.x;         e[u][5] = __int_as_float(q3.y);
            offs[u][6] = q3.z;         e[u][6] = __int_as_float(q3.w);
            offs[u][7] = q4.x;         e[u][7] = __int_as_float(q4.y);
        }

        if (act) {
            __half2 r[UNROLL][KK], rm[UNROLL];
#pragma unroll
            for (int u = 0; u < UNROLL; ++u) {
#pragma unroll
                for (int k = 0; k < KK; ++k) r[u][k] = R16[offs[u][k] + t];
            }
#pragma unroll
            for (int u = 0; u < UNROLL; ++u) rm[u] = R16[offm[u] + t];

#pragma unroll
            for (int u = 0; u < UNROLL; ++u) {
                float2 f = __half22float2(r[u][0]);
                float mx = f.x * e[u][0], my = f.y * e[u][0];
#pragma unroll
                for (int k = 1; k < KK; ++k) {
                    f = __half22float2(r[u][k]);
                    mx = fmaxf(mx, f.x * e[u][k]);
                    my = fmaxf(my, f.y * e[u][k]);
                }
                const float2 rf = __half22float2(rm[u]);
                const float n = nn[u], a = 1.f - nn[u];
                accx = fmaf(a, mx, fmaf(n, rf.x, accx));
                accy = fmaf(a, my, fmaf(n, rf.y, accy));
            }
        }
    }
    if (act) {
        atomicAdd(&X[b * DD + 2*t],     accx);
        atomicAdd(&X[b * DD + 2*t + 1], accy);
    }
}

// FC (300->14) + ReLU + softmax. One block per batch row, 16 lanes per class.
__global__ __launch_bounds__(256) void fc_softmax(
    const float* __restrict__ X, const float* __restrict__ W,
    const float* __restrict__ bias, float* __restrict__ out)
{
    const int b = blockIdx.x;
    const int t = threadIdx.x;
    const int c = t >> 4;
    const int j = t & 15;
    __shared__ float h[CC];

    if (c < CC) {
        float acc = 0.f;
        const float* x = X + b * DD;
        const float* w = W + c * DD;
        for (int d = j; d < DD; d += 16) acc += x[d] * w[d];
#pragma unroll
        for (int off = 8; off > 0; off >>= 1) acc += __shfl_down(acc, off, 16);
        if (j == 0) h[c] = fmaxf(acc + bias[c], 0.f);
    }
    __syncthreads();
    if (t < CC) {
        float mx = -INFINITY;
#pragma unroll
        for (int i = 0; i < CC; ++i) mx = fmaxf(mx, h[i]);
        float s = 0.f;
#pragma unroll
        for (int i = 0; i < CC; ++i) s += expf(h[i] - mx);
        out[b * CC + t] = expf(h[t] - mx) / s;
    }
}

extern "C" void kernel_launch(void* const* d_in, const int* in_sizes, int n_in,
                              void* d_out, int out_size, void* d_ws, size_t ws_size,
                              hipStream_t stream) {
    const int*   master = (const int*)d_in[0];
    const int*   slaves = (const int*)d_in[1];
    const int*   edges  = (const int*)d_in[2];
    const float* R      = (const float*)d_in[3];
    const float* E      = (const float*)d_in[4];
    const float* N      = (const float*)d_in[5];
    const float* W      = (const float*)d_in[6];
    const float* bias   = (const float*)d_in[7];
    float* out = (float*)d_out;

    // ws layout (bytes): R16 [2,943,104] | X [153,600] | rec [5,242,880]
    char* ws = (char*)d_ws;
    __half2* R16 = (__half2*)ws;
    float*   X   = (float*)(ws + 2943104);
    int*     rec = (int*)(ws + 2943104 + 153600);

    prep<<<(R_H2_ELEMS + 255) / 256, 256, 0, stream>>>(
        (const float2*)R, edges, E, master, N, slaves, R16, rec, X);

    dim3 grid(BB, LL / L_PER_BLOCK);
    gnn_agg<<<grid, 192, 0, stream>>>((const int4*)rec, R16, X);

    fc_softmax<<<BB, 256, 0, stream>>>(X, W, bias, out);
}

// Round 7
// 192.893 us; speedup vs baseline: 1.3555x; 1.0080x over previous
//
#include <hip/hip_runtime.h>
#include <hip/hip_fp16.h>
#include <math.h>

#define BB 128
#define LL 512
#define KK 8
#define DD 300
#define D2 150          // D in half2 units
#define CC 14
#define L_PER_BLOCK 8
#define UNROLL 4

#define R_H2_ELEMS ((4905 * 300) / 2)   // 735750
#define R_F4_ELEMS ((4905 * 300) / 4)   // 367875
#define REC_INTS 20                     // per-l record: [off_m, nn, (off_s,e)*8, pad2]

// Fused prep:
//  - convert R fp32 -> half2 table (2.94 MB, per-XCD-L2-resident), float4-vectorized
//  - resolve all random E / N gathers (one thread per edge: max MLP)
//  - write packed per-l records with pre-scaled row offsets
//  - zero X accumulator
__global__ __launch_bounds__(256) void prep(
    const float4* __restrict__ R4, const int* __restrict__ edges,
    const float* __restrict__ E, const int* __restrict__ master,
    const float* __restrict__ N, const int* __restrict__ slaves,
    __half2* __restrict__ R16, int* __restrict__ rec, float* __restrict__ X)
{
    const int i = blockIdx.x * 256 + threadIdx.x;

    if (i < R_F4_ELEMS) {
        const float4 f = R4[i];
        R16[2 * i]     = __floats2half2_rn(f.x, f.y);
        R16[2 * i + 1] = __floats2half2_rn(f.z, f.w);
    }
    if (i < BB * LL * KK) {                       // one edge each
        const int bl = i >> 3, k = i & 7;
        rec[bl * REC_INTS + 2 + 2 * k] = slaves[i] * D2;
        rec[bl * REC_INTS + 3 + 2 * k] = __float_as_int(E[edges[i]]);
    }
    if (i < BB * LL) {                            // master + gate
        const int m = master[i];
        rec[i * REC_INTS]     = m * D2;
        rec[i * REC_INTS + 1] = __float_as_int(N[m]);
    }
    if (i < BB * DD) X[i] = 0.f;
}

// X[b,d] = sum_l [ (1-nn)*max_k(R[s_k,d]*e_k) + nn*R[m,d] ]
// 192 threads, t<150 owns one half2 of D. Records read via uniform int4
// (-> s_load_dwordx4); 4-deep l unroll = 36 independent L2-hit gathers.
// Grid (128, 64) = 8192 blocks for full wave-slot saturation.
__global__ __launch_bounds__(192) void gnn_agg(
    const int4* __restrict__ rec4, const __half2* __restrict__ R16,
    float* __restrict__ X)
{
    const int b  = blockIdx.x;
    const int lc = blockIdx.y;
    const int t  = threadIdx.x;
    const bool act = (t < D2);

    float accx = 0.f, accy = 0.f;
    const int bl_base = b * LL + lc * L_PER_BLOCK;

    for (int lg = 0; lg < L_PER_BLOCK; lg += UNROLL) {
        int   offm[UNROLL], offs[UNROLL][KK];
        float nn[UNROLL], e[UNROLL][KK];

#pragma unroll
        for (int u = 0; u < UNROLL; ++u) {
            const int4* r = rec4 + (long)(bl_base + lg + u) * (REC_INTS / 4);
            const int4 q0 = r[0];   // off_m, nn, off_s0, e0
            const int4 q1 = r[1];   // off_s1, e1, off_s2, e2
            const int4 q2 = r[2];   // off_s3, e3, off_s4, e4
            const int4 q3 = r[3];   // off_s5, e5, off_s6, e6
            const int4 q4 = r[4];   // off_s7, e7, pad, pad
            offm[u] = q0.x;            nn[u]   = __int_as_float(q0.y);
            offs[u][0] = q0.z;         e[u][0] = __int_as_float(q0.w);
            offs[u][1] = q1.x;         e[u][1] = __int_as_float(q1.y);
            offs[u][2] = q1.z;         e[u][2] = __int_as_float(q1.w);
            offs[u][3] = q2.x;         e[u][3] = __int_as_float(q2.y);
            offs[u][4] = q2.z;         e[u][4] = __int_as_float(q2.w);
            offs[u][5] = q3.x;         e[u][5] = __int_as_float(q3.y);
            offs[u][6] = q3.z;         e[u][6] = __int_as_float(q3.w);
            offs[u][7] = q4.x;         e[u][7] = __int_as_float(q4.y);
        }

        if (act) {
            __half2 r[UNROLL][KK], rm[UNROLL];
#pragma unroll
            for (int u = 0; u < UNROLL; ++u) {
#pragma unroll
                for (int k = 0; k < KK; ++k) r[u][k] = R16[offs[u][k] + t];
            }
#pragma unroll
            for (int u = 0; u < UNROLL; ++u) rm[u] = R16[offm[u] + t];

#pragma unroll
            for (int u = 0; u < UNROLL; ++u) {
                float2 f = __half22float2(r[u][0]);
                float mx = f.x * e[u][0], my = f.y * e[u][0];
#pragma unroll
                for (int k = 1; k < KK; ++k) {
                    f = __half22float2(r[u][k]);
                    mx = fmaxf(mx, f.x * e[u][k]);
                    my = fmaxf(my, f.y * e[u][k]);
                }
                const float2 rf = __half22float2(rm[u]);
                const float n = nn[u], a = 1.f - nn[u];
                accx = fmaf(a, mx, fmaf(n, rf.x, accx));
                accy = fmaf(a, my, fmaf(n, rf.y, accy));
            }
        }
    }
    if (act) {
        atomicAdd(&X[b * DD + 2*t],     accx);
        atomicAdd(&X[b * DD + 2*t + 1], accy);
    }
}

// FC (300->14) + ReLU + softmax. One block per batch row, 16 lanes per class.
__global__ __launch_bounds__(256) void fc_softmax(
    const float* __restrict__ X, const float* __restrict__ W,
    const float* __restrict__ bias, float* __restrict__ out)
{
    const int b = blockIdx.x;
    const int t = threadIdx.x;
    const int c = t >> 4;
    const int j = t & 15;
    __shared__ float h[CC];

    if (c < CC) {
        float acc = 0.f;
        const float* x = X + b * DD;
        const float* w = W + c * DD;
        for (int d = j; d < DD; d += 16) acc += x[d] * w[d];
#pragma unroll
        for (int off = 8; off > 0; off >>= 1) acc += __shfl_down(acc, off, 16);
        if (j == 0) h[c] = fmaxf(acc + bias[c], 0.f);
    }
    __syncthreads();
    if (t < CC) {
        float mx = -INFINITY;
#pragma unroll
        for (int i = 0; i < CC; ++i) mx = fmaxf(mx, h[i]);
        float s = 0.f;
#pragma unroll
        for (int i = 0; i < CC; ++i) s += expf(h[i] - mx);
        out[b * CC + t] = expf(h[t] - mx) / s;
    }
}

extern "C" void kernel_launch(void* const* d_in, const int* in_sizes, int n_in,
                              void* d_out, int out_size, void* d_ws, size_t ws_size,
                              hipStream_t stream) {
    const int*   master = (const int*)d_in[0];
    const int*   slaves = (const int*)d_in[1];
    const int*   edges  = (const int*)d_in[2];
    const float* R      = (const float*)d_in[3];
    const float* E      = (const float*)d_in[4];
    const float* N      = (const float*)d_in[5];
    const float* W      = (const float*)d_in[6];
    const float* bias   = (const float*)d_in[7];
    float* out = (float*)d_out;

    // ws layout (bytes): R16 [2,943,104] | X [153,600] | rec [5,242,880]
    char* ws = (char*)d_ws;
    __half2* R16 = (__half2*)ws;
    float*   X   = (float*)(ws + 2943104);
    int*     rec = (int*)(ws + 2943104 + 153600);

    prep<<<(BB * LL * KK) / 256, 256, 0, stream>>>(
        (const float4*)R, edges, E, master, N, slaves, R16, rec, X);

    dim3 grid(BB, LL / L_PER_BLOCK);
    gnn_agg<<<grid, 192, 0, stream>>>((const int4*)rec, R16, X);

    fc_softmax<<<BB, 256, 0, stream>>>(X, W, bias, out);
}

// Round 8
// 192.060 us; speedup vs baseline: 1.3614x; 1.0043x over previous
//
#include <hip/hip_runtime.h>
#include <hip/hip_fp16.h>
#include <math.h>

#define BB 128
#define LL 512
#define KK 8
#define DD 300
#define D2 150          // D in half2 units
#define CC 14
#define L_PER_BLOCK 8
#define UNROLL 4

#define R_H2_ELEMS ((4905 * 300) / 2)   // 735750
#define R_F4_ELEMS ((4905 * 300) / 4)   // 367875
#define REC_INTS 20                     // per-l record: [off_m, nn, (off_s,e16x2)*8, pad2]

typedef _Float16 h2 __attribute__((ext_vector_type(2)));

// Fused prep:
//  - convert R fp32 -> fp16-pair table (2.94 MB, per-XCD-L2-resident)
//  - resolve all random E / N gathers (one thread per edge: max MLP)
//  - write packed per-l records: row offsets pre-scaled, e pre-packed as
//    duplicated fp16 pair (used directly as v_pk_mul_f16 operand)
//  - zero X accumulator
__global__ __launch_bounds__(256) void prep(
    const float4* __restrict__ R4, const int* __restrict__ edges,
    const float* __restrict__ E, const int* __restrict__ master,
    const float* __restrict__ N, const int* __restrict__ slaves,
    h2* __restrict__ R16, int* __restrict__ rec, float* __restrict__ X)
{
    const int i = blockIdx.x * 256 + threadIdx.x;

    if (i < R_F4_ELEMS) {
        const float4 f = R4[i];
        h2 a; a.x = (_Float16)f.x; a.y = (_Float16)f.y;
        h2 b; b.x = (_Float16)f.z; b.y = (_Float16)f.w;
        R16[2 * i]     = a;
        R16[2 * i + 1] = b;
    }
    if (i < BB * LL * KK) {                       // one edge each
        const int bl = i >> 3, k = i & 7;
        rec[bl * REC_INTS + 2 + 2 * k] = slaves[i] * D2;
        const _Float16 ev = (_Float16)E[edges[i]];
        h2 p; p.x = ev; p.y = ev;
        rec[bl * REC_INTS + 3 + 2 * k] = __builtin_bit_cast(int, p);
    }
    if (i < BB * LL) {                            // master + gate
        const int m = master[i];
        rec[i * REC_INTS]     = m * D2;
        rec[i * REC_INTS + 1] = __float_as_int(N[m]);
    }
    if (i < BB * DD) X[i] = 0.f;
}

// X[b,d] = sum_l [ (1-nn)*max_k(R[s_k,d]*e_k) + nn*R[m,d] ]
// 192 threads, t<150 owns one fp16 pair of D. Records read via uniform int4
// (-> s_load_dwordx4); mul/max in packed fp16 (v_pk_*), accumulate fp32.
// 4-deep l unroll = 36 independent L2-hit gathers per thread.
__global__ __launch_bounds__(192) void gnn_agg(
    const int4* __restrict__ rec4, const h2* __restrict__ Rv,
    float* __restrict__ X)
{
    const int b  = blockIdx.x;
    const int lc = blockIdx.y;
    const int t  = threadIdx.x;
    const bool act = (t < D2);

    float accx = 0.f, accy = 0.f;
    const int bl_base = b * LL + lc * L_PER_BLOCK;

    for (int lg = 0; lg < L_PER_BLOCK; lg += UNROLL) {
        int   offm[UNROLL], offs[UNROLL][KK], eb[UNROLL][KK];
        float nn[UNROLL];

#pragma unroll
        for (int u = 0; u < UNROLL; ++u) {
            const int4* r = rec4 + (long)(bl_base + lg + u) * (REC_INTS / 4);
            const int4 q0 = r[0];   // off_m, nn, off_s0, e0
            const int4 q1 = r[1];   // off_s1, e1, off_s2, e2
            const int4 q2 = r[2];   // off_s3, e3, off_s4, e4
            const int4 q3 = r[3];   // off_s5, e5, off_s6, e6
            const int4 q4 = r[4];   // off_s7, e7, pad, pad
            offm[u] = q0.x;            nn[u]    = __int_as_float(q0.y);
            offs[u][0] = q0.z;         eb[u][0] = q0.w;
            offs[u][1] = q1.x;         eb[u][1] = q1.y;
            offs[u][2] = q1.z;         eb[u][2] = q1.w;
            offs[u][3] = q2.x;         eb[u][3] = q2.y;
            offs[u][4] = q2.z;         eb[u][4] = q2.w;
            offs[u][5] = q3.x;         eb[u][5] = q3.y;
            offs[u][6] = q3.z;         eb[u][6] = q3.w;
            offs[u][7] = q4.x;         eb[u][7] = q4.y;
        }

        if (act) {
            h2 r[UNROLL][KK], rm[UNROLL];
#pragma unroll
            for (int u = 0; u < UNROLL; ++u) {
#pragma unroll
                for (int k = 0; k < KK; ++k) r[u][k] = (Rv + offs[u][k])[t];
            }
#pragma unroll
            for (int u = 0; u < UNROLL; ++u) rm[u] = (Rv + offm[u])[t];

#pragma unroll
            for (int u = 0; u < UNROLL; ++u) {
                h2 mx = r[u][0] * __builtin_bit_cast(h2, eb[u][0]);
#pragma unroll
                for (int k = 1; k < KK; ++k)
                    mx = __builtin_elementwise_max(
                        mx, r[u][k] * __builtin_bit_cast(h2, eb[u][k]));
                const float n = nn[u], a = 1.f - n;
                accx = fmaf(a, (float)mx.x, fmaf(n, (float)rm[u].x, accx));
                accy = fmaf(a, (float)mx.y, fmaf(n, (float)rm[u].y, accy));
            }
        }
    }
    if (act) {
        atomicAdd(&X[b * DD + 2*t],     accx);
        atomicAdd(&X[b * DD + 2*t + 1], accy);
    }
}

// FC (300->14) + ReLU + softmax. One block per batch row, 16 lanes per class.
__global__ __launch_bounds__(256) void fc_softmax(
    const float* __restrict__ X, const float* __restrict__ W,
    const float* __restrict__ bias, float* __restrict__ out)
{
    const int b = blockIdx.x;
    const int t = threadIdx.x;
    const int c = t >> 4;
    const int j = t & 15;
    __shared__ float h[CC];

    if (c < CC) {
        float acc = 0.f;
        const float* x = X + b * DD;
        const float* w = W + c * DD;
        for (int d = j; d < DD; d += 16) acc += x[d] * w[d];
#pragma unroll
        for (int off = 8; off > 0; off >>= 1) acc += __shfl_down(acc, off, 16);
        if (j == 0) h[c] = fmaxf(acc + bias[c], 0.f);
    }
    __syncthreads();
    if (t < CC) {
        float mx = -INFINITY;
#pragma unroll
        for (int i = 0; i < CC; ++i) mx = fmaxf(mx, h[i]);
        float s = 0.f;
#pragma unroll
        for (int i = 0; i < CC; ++i) s += expf(h[i] - mx);
        out[b * CC + t] = expf(h[t] - mx) / s;
    }
}

extern "C" void kernel_launch(void* const* d_in, const int* in_sizes, int n_in,
                              void* d_out, int out_size, void* d_ws, size_t ws_size,
                              hipStream_t stream) {
    const int*   master = (const int*)d_in[0];
    const int*   slaves = (const int*)d_in[1];
    const int*   edges  = (const int*)d_in[2];
    const float* R      = (const float*)d_in[3];
    const float* E      = (const float*)d_in[4];
    const float* N      = (const float*)d_in[5];
    const float* W      = (const float*)d_in[6];
    const float* bias   = (const float*)d_in[7];
    float* out = (float*)d_out;

    // ws layout (bytes): R16 [2,943,104] | X [153,600] | rec [5,242,880]
    char* ws = (char*)d_ws;
    h2*    R16 = (h2*)ws;
    float* X   = (float*)(ws + 2943104);
    int*   rec = (int*)(ws + 2943104 + 153600);

    prep<<<(BB * LL * KK) / 256, 256, 0, stream>>>(
        (const float4*)R, edges, E, master, N, slaves, R16, rec, X);

    dim3 grid(BB, LL / L_PER_BLOCK);
    gnn_agg<<<grid, 192, 0, stream>>>((const int4*)rec, R16, X);

    fc_softmax<<<BB, 256, 0, stream>>>(X, W, bias, out);
}

// Round 9
// 189.491 us; speedup vs baseline: 1.3798x; 1.0136x over previous
//
#include <hip/hip_runtime.h>
#include <hip/hip_fp16.h>
#include <math.h>

#define BB 128
#define LL 512
#define KK 8
#define DD 300
#define D2 150          // D in fp16-pair units
#define CC 14
#define L_PER_BLOCK 8
#define UNROLL 4

#define R_F4_ELEMS ((4905 * 300) / 4)   // 367875

typedef _Float16 h2 __attribute__((ext_vector_type(2)));

// prep: convert R fp32 -> fp16-pair table (2.94 MB, per-XCD-L2-resident)
// and zero the X accumulator. E/N gathers are fused into gnn_agg now.
__global__ __launch_bounds__(256) void prep(
    const float4* __restrict__ R4, h2* __restrict__ R16, float* __restrict__ X)
{
    const int i = blockIdx.x * 256 + threadIdx.x;
    if (i < R_F4_ELEMS) {
        const float4 f = R4[i];
        h2 a; a.x = (_Float16)f.x; a.y = (_Float16)f.y;
        h2 b; b.x = (_Float16)f.z; b.y = (_Float16)f.w;
        R16[2 * i]     = a;
        R16[2 * i + 1] = b;
    }
    if (i < BB * DD) X[i] = 0.f;
}

// X[b,d] = sum_l [ (1-nn)*max_k(R[s_k,d]*e_k) + nn*R[m,d] ]
// Block = 8 l's. Phase 0: 64 threads gather this block's E values (random,
// HBM) + 8 N gates into LDS — latency absorbed by cross-block overlap.
// Phase 1: t<150 owns one fp16 pair of D; slave/master indices read at
// wave-uniform addresses (-> s_load); e via broadcast ds_read_b128;
// packed-fp16 mul/max, fp32 accumulate. 36 independent L2-hit gathers.
__global__ __launch_bounds__(192) void gnn_agg(
    const int* __restrict__ master, const int* __restrict__ slaves,
    const int* __restrict__ edges, const float* __restrict__ E,
    const float* __restrict__ N, const h2* __restrict__ Rv,
    float* __restrict__ X)
{
    const int b  = blockIdx.x;
    const int lc = blockIdx.y;
    const int t  = threadIdx.x;
    const bool act = (t < D2);
    const int bl_base = b * LL + lc * L_PER_BLOCK;

    __shared__ __align__(16) int ebuf[L_PER_BLOCK * KK];
    __shared__ float nnbuf[L_PER_BLOCK];

    if (t < L_PER_BLOCK * KK) {                 // 64 random E gathers
        const _Float16 ev = (_Float16)E[edges[bl_base * KK + t]];
        h2 p; p.x = ev; p.y = ev;
        ebuf[t] = __builtin_bit_cast(int, p);
    } else if (t < L_PER_BLOCK * KK + L_PER_BLOCK) {
        const int l = t - L_PER_BLOCK * KK;
        nnbuf[l] = N[master[bl_base + l]];
    }
    __syncthreads();

    float accx = 0.f, accy = 0.f;

    for (int lg = 0; lg < L_PER_BLOCK; lg += UNROLL) {
        int   offm[UNROLL], offs[UNROLL][KK];
        int4  ea[UNROLL], eb2[UNROLL];
        float nn[UNROLL];

#pragma unroll
        for (int u = 0; u < UNROLL; ++u) {
            const int bl = bl_base + lg + u;
            offm[u] = master[bl] * D2;          // wave-uniform -> scalar
#pragma unroll
            for (int k = 0; k < KK; ++k)
                offs[u][k] = slaves[bl * KK + k] * D2;   // scalar
            ea[u]  = *(const int4*)&ebuf[(lg + u) * KK];     // broadcast LDS
            eb2[u] = *(const int4*)&ebuf[(lg + u) * KK + 4];
            nn[u]  = nnbuf[lg + u];
        }

        if (act) {
            h2 r[UNROLL][KK], rm[UNROLL];
#pragma unroll
            for (int u = 0; u < UNROLL; ++u) {
#pragma unroll
                for (int k = 0; k < KK; ++k) r[u][k] = (Rv + offs[u][k])[t];
            }
#pragma unroll
            for (int u = 0; u < UNROLL; ++u) rm[u] = (Rv + offm[u])[t];

#pragma unroll
            for (int u = 0; u < UNROLL; ++u) {
                const int ev[KK] = { ea[u].x, ea[u].y, ea[u].z, ea[u].w,
                                     eb2[u].x, eb2[u].y, eb2[u].z, eb2[u].w };
                h2 mx = r[u][0] * __builtin_bit_cast(h2, ev[0]);
#pragma unroll
                for (int k = 1; k < KK; ++k)
                    mx = __builtin_elementwise_max(
                        mx, r[u][k] * __builtin_bit_cast(h2, ev[k]));
                const float n = nn[u], a = 1.f - n;
                accx = fmaf(a, (float)mx.x, fmaf(n, (float)rm[u].x, accx));
                accy = fmaf(a, (float)mx.y, fmaf(n, (float)rm[u].y, accy));
            }
        }
    }
    if (act) {
        atomicAdd(&X[b * DD + 2*t],     accx);
        atomicAdd(&X[b * DD + 2*t + 1], accy);
    }
}

// FC (300->14) + ReLU + softmax. One block per batch row, 16 lanes per class.
__global__ __launch_bounds__(256) void fc_softmax(
    const float* __restrict__ X, const float* __restrict__ W,
    const float* __restrict__ bias, float* __restrict__ out)
{
    const int b = blockIdx.x;
    const int t = threadIdx.x;
    const int c = t >> 4;
    const int j = t & 15;
    __shared__ float h[CC];

    if (c < CC) {
        float acc = 0.f;
        const float* x = X + b * DD;
        const float* w = W + c * DD;
        for (int d = j; d < DD; d += 16) acc += x[d] * w[d];
#pragma unroll
        for (int off = 8; off > 0; off >>= 1) acc += __shfl_down(acc, off, 16);
        if (j == 0) h[c] = fmaxf(acc + bias[c], 0.f);
    }
    __syncthreads();
    if (t < CC) {
        float mx = -INFINITY;
#pragma unroll
        for (int i = 0; i < CC; ++i) mx = fmaxf(mx, h[i]);
        float s = 0.f;
#pragma unroll
        for (int i = 0; i < CC; ++i) s += expf(h[i] - mx);
        out[b * CC + t] = expf(h[t] - mx) / s;
    }
}

extern "C" void kernel_launch(void* const* d_in, const int* in_sizes, int n_in,
                              void* d_out, int out_size, void* d_ws, size_t ws_size,
                              hipStream_t stream) {
    const int*   master = (const int*)d_in[0];
    const int*   slaves = (const int*)d_in[1];
    const int*   edges  = (const int*)d_in[2];
    const float* R      = (const float*)d_in[3];
    const float* E      = (const float*)d_in[4];
    const float* N      = (const float*)d_in[5];
    const float* W      = (const float*)d_in[6];
    const float* bias   = (const float*)d_in[7];
    float* out = (float*)d_out;

    // ws layout (bytes): R16 [2,943,104] | X [153,600]
    char* ws = (char*)d_ws;
    h2*    R16 = (h2*)ws;
    float* X   = (float*)(ws + 2943104);

    prep<<<(R_F4_ELEMS + 255) / 256, 256, 0, stream>>>(
        (const float4*)R, R16, X);

    dim3 grid(BB, LL / L_PER_BLOCK);
    gnn_agg<<<grid, 192, 0, stream>>>(master, slaves, edges, E, N, R16, X);

    fc_softmax<<<BB, 256, 0, stream>>>(X, W, bias, out);
}